// Round 11
// baseline (120.588 us; speedup 1.0000x reference)
//
#include <hip/hip_runtime.h>
#include <hip/hip_bf16.h>

typedef __attribute__((ext_vector_type(8))) short vbf8;   // 8 bf16 in 4 VGPRs
typedef __attribute__((ext_vector_type(4))) float vf4;    // MFMA 16x16 accumulator
typedef __attribute__((ext_vector_type(4))) unsigned int vu4;

#define MFMA16(a, b, c) __builtin_amdgcn_mfma_f32_16x16x32_bf16((a), (b), (c), 0, 0, 0)

__device__ __forceinline__ unsigned short f2bf(float f) {
    unsigned int u = __float_as_uint(f);
    u += 0x7fffu + ((u >> 16) & 1u);   // RNE
    return (unsigned short)(u >> 16);
}

// packed f32x2 -> bf16x2 (RNE), non-volatile so the scheduler can reorder
__device__ __forceinline__ unsigned int cvtpk(float a, float b) {
    unsigned int r;
    asm("v_cvt_pk_bf16_f32 %0, %1, %2" : "=v"(r) : "v"(a), "v"(b));
    return r;
}

// async global->LDS, 16B per lane. LDS dest must be linear (base + lane*16).
__device__ __forceinline__ void gload_lds16(const void* g, void* l) {
    __builtin_amdgcn_global_load_lds(
        (const __attribute__((address_space(1))) unsigned int*)(unsigned long long)g,
        (__attribute__((address_space(3))) unsigned int*)(unsigned long long)l,
        16, 0, 0);
}

// ---------------- fused f32 -> bf16 conversion (x, w_qkv, w_out in one launch) ----------------
__global__ __launch_bounds__(256) void cvt_all(
    const float* __restrict__ x, const float* __restrict__ wq, const float* __restrict__ wo,
    unsigned short* __restrict__ xb, unsigned short* __restrict__ wqb, unsigned short* __restrict__ wob)
{
    int i = blockIdx.x * 256 + threadIdx.x;   // float4 index, total 2097152
    const float* src;
    unsigned short* dst;
    int off;
    if (i < 1048576)      { src = x;  dst = xb;  off = i; }
    else if (i < 1835008) { src = wq; dst = wqb; off = i - 1048576; }
    else                  { src = wo; dst = wob; off = i - 1835008; }
    float4 v = ((const float4*)src)[off];
    ushort4 o;
    o.x = f2bf(v.x); o.y = f2bf(v.y); o.z = f2bf(v.z); o.w = f2bf(v.w);
    ((ushort4*)dst)[off] = o;
}

// ---------------- GEMM: C[M,N] = A[M,K] * Bt[N,K]^T, bf16 in, f32 acc ----------------
// BM=128, BN=NT*32 (NT=4 -> 128, NT=2 -> 64), BK=64, 4 waves (2x2).
// LDS linear, global source pre-swizzled; XCD-chunked block swizzle (T1).
// EPI=0: write f32 to Cf[M,N] via LDS-transposed coalesced epilogue.
// EPI=1: scatter bf16 into Q (pre-scaled by 0.125*log2e) / K [bh][t][64] (LDS round-trip,
//        fully coalesced 16B stores) and V TRANSPOSED [bh][64][2048] (direct ushort4).
template <int EPI, int NT>
__global__ __launch_bounds__(256) void gemm_bt(
    const unsigned short* __restrict__ A, const unsigned short* __restrict__ Bt,
    int M, int N, int K,
    float* __restrict__ Cf,
    unsigned short* __restrict__ Qo, unsigned short* __restrict__ Ko, unsigned short* __restrict__ Vo)
{
    __shared__ __align__(16) unsigned short s[128 * 64 + NT * 32 * 64];
    unsigned short* sA = s;
    unsigned short* sB = s + 128 * 64;

    const int tid = threadIdx.x;
    const int lane = tid & 63;
    const int w = tid >> 6;
    const int wr = w >> 1, wc = w & 1;
    const int l16 = lane & 15, lhi = lane >> 4;

    // XCD-aware bijective swizzle (grid size % 8 == 0 for all instantiations here)
    const int nbx = gridDim.x;
    const int lin = blockIdx.y * nbx + blockIdx.x;
    const int cpx = (nbx * gridDim.y) >> 3;
    const int swz = (lin & 7) * cpx + (lin >> 3);
    const int bm = swz / nbx, bn = swz % nbx;
    const int row0 = bm * 128, col0 = bn * (NT * 32);

    vf4 acc[4][NT] = {};

    for (int k0 = 0; k0 < K; k0 += 64) {
        // stage A: 128x64 = 1024 chunks (4/thread)
#pragma unroll
        for (int i = 0; i < 4; ++i) {
            int p = i * 256 + tid;
            int r = p >> 3, cb = p & 7;
            int cs = cb ^ (r & 7);
            gload_lds16(A + (size_t)(row0 + r) * K + k0 + (cs << 3), &sA[p << 3]);
        }
        // stage B: (NT*32)x64 chunks (NT/thread)
#pragma unroll
        for (int i = 0; i < NT; ++i) {
            int p = i * 256 + tid;
            int r = p >> 3, cb = p & 7;
            int cs = cb ^ (r & 7);
            gload_lds16(Bt + (size_t)(col0 + r) * K + k0 + (cs << 3), &sB[p << 3]);
        }
        __syncthreads();
#pragma unroll
        for (int kk = 0; kk < 2; ++kk) {
            const int cb = kk * 4 + lhi;
            vbf8 af[4], bfr[NT];
#pragma unroll
            for (int mt = 0; mt < 4; ++mt) {
                int r = wr * 64 + mt * 16 + l16;
                af[mt] = *(const vbf8*)&sA[(r << 6) + ((cb ^ (r & 7)) << 3)];
            }
#pragma unroll
            for (int nt = 0; nt < NT; ++nt) {
                int r = wc * (NT * 16) + nt * 16 + l16;
                bfr[nt] = *(const vbf8*)&sB[(r << 6) + ((cb ^ (r & 7)) << 3)];
            }
#pragma unroll
            for (int mt = 0; mt < 4; ++mt)
#pragma unroll
                for (int nt = 0; nt < NT; ++nt)
                    acc[mt][nt] = MFMA16(af[mt], bfr[nt], acc[mt][nt]);
        }
        __syncthreads();
    }

    // -------- epilogue --------
    // C/D fragment layout: col = lane&15, row = (lane>>4)*4 + r
    if (EPI == 1) {
        const int which = col0 >> 10;         // block-uniform (128-col tile, 1024-aligned bands)
        const int b = row0 >> 11;             // block-uniform (128-row tile, 2048-aligned)
        const int t0 = row0 & 2047;           // row within batch (BUGFIX vs R10: was row0)
        if (which == 2) {
            // V: direct transposed stores; 4 consecutive r = 4 consecutive t at fixed d
#pragma unroll
            for (int mt = 0; mt < 4; ++mt) {
#pragma unroll
                for (int nt = 0; nt < 4; ++nt) {
                    int row = row0 + wr * 64 + mt * 16 + lhi * 4;
                    int col = col0 + wc * 64 + nt * 16 + l16;
                    int h = (col >> 6) & 15, d = col & 63;
                    int t = row & 2047;
                    size_t bh = (size_t)(b * 16 + h);
                    ushort4 pv;
                    pv.x = f2bf(acc[mt][nt][0]);
                    pv.y = f2bf(acc[mt][nt][1]);
                    pv.z = f2bf(acc[mt][nt][2]);
                    pv.w = f2bf(acc[mt][nt][3]);
                    *(ushort4*)&Vo[(bh * 64 + d) * 2048 + t] = pv;
                }
            }
        } else {
            // Q/K: LDS round-trip (swizzled) -> fully coalesced 16B stores
            unsigned short* sC = s;           // 128x128 bf16 = 32 KB
            const float qs = 0.18033688011112042f;   // 0.125 * log2(e)
#pragma unroll
            for (int mt = 0; mt < 4; ++mt)
#pragma unroll
                for (int nt = 0; nt < 4; ++nt)
#pragma unroll
                    for (int r = 0; r < 4; ++r) {
                        int lr = wr * 64 + mt * 16 + lhi * 4 + r;
                        int lc = wc * 64 + nt * 16 + l16;
                        float v = acc[mt][nt][r];
                        sC[lr * 128 + (lc ^ ((lr & 7) << 3))] =
                            (which == 0) ? f2bf(v * qs) : f2bf(v);
                    }
            __syncthreads();
            unsigned short* dstbuf = (which == 0) ? Qo : Ko;
#pragma unroll
            for (int hf = 0; hf < 2; ++hf) {
                int h = ((col0 >> 6) + hf) & 15;
                unsigned short* base = dstbuf + ((size_t)(b * 16 + h) * 2048 + t0) * 64;
#pragma unroll
                for (int j = 0; j < 4; ++j) {
                    int ch = j * 256 + tid;       // 1024 chunks of 16B per half
                    int tl = ch >> 3, dc = ch & 7;
                    vbf8 vv = *(const vbf8*)&sC[tl * 128 + hf * 64 + ((dc ^ (tl & 7)) << 3)];
                    *(vbf8*)&base[(size_t)tl * 64 + dc * 8] = vv;
                }
            }
        }
    } else {
        // f32 out: two 64-row halves through LDS (swizzled), float4 coalesced stores
        float* sCf = (float*)s;               // 64x64 f32 = 16 KB (fits 24 KB)
#pragma unroll
        for (int h2 = 0; h2 < 2; ++h2) {
            if (wr == h2) {
#pragma unroll
                for (int mt = 0; mt < 4; ++mt)
#pragma unroll
                    for (int nt = 0; nt < NT; ++nt)
#pragma unroll
                        for (int r = 0; r < 4; ++r) {
                            int lr = mt * 16 + lhi * 4 + r;
                            int lc = wc * (NT * 16) + nt * 16 + l16;
                            sCf[lr * 64 + (lc ^ ((lr & 7) << 2))] = acc[mt][nt][r];
                        }
            }
            __syncthreads();
#pragma unroll
            for (int j = 0; j < 4; ++j) {
                int ch = j * 256 + tid;           // 1024 chunks of 16B (4 f32)
                int rl = ch >> 4, cc = ch & 15;
                float4 vv = *(const float4*)&sCf[rl * 64 + ((cc * 4) ^ ((rl & 7) << 2))];
                *(float4*)&Cf[(size_t)(row0 + h2 * 64 + rl) * N + col0 + cc * 4] = vv;
            }
            __syncthreads();
        }
    }
}

// ---------------- causal flash attention, 8 waves / 128 q rows, double-buffered KV ----------------
// (R4-proven structure: KVBLK=128, counted vmcnt, band pairing.)
// Q/K: [32 bh][2048][64] bf16 (Q pre-scaled by 0.125*log2e); Vt: [32 bh][64][2048] bf16.
// S^T = mfma(K, Q): lane owns one q column; softmax in-lane (exp2, defer-max) + 2 shfl;
// P packed via v_cvt_pk_bf16_f32, redistributed by shfl; O^T = mfma(V^T, P^T).
__global__ __launch_bounds__(512, 4) void attn_fwd4(
    const unsigned short* __restrict__ Q, const unsigned short* __restrict__ Kp,
    const unsigned short* __restrict__ Vt, unsigned short* __restrict__ att)
{
    __shared__ __align__(16) unsigned short sK[2][128 * 64];   // [t][d]
    __shared__ __align__(16) unsigned short sV[2][64 * 128];   // [d][t]

    const int tid = threadIdx.x;
    const int lane = tid & 63;
    const int w = tid >> 6;                    // 0..7
    const int l16 = lane & 15, lhi = lane >> 4;
    const int bh = blockIdx.x & 31;
    // band pairing for load balance: order 15..8 then 0..7 so the two co-resident
    // blocks per CU sum to ~15-16 tile-iterations instead of 10..24.
    const int j = blockIdx.x >> 5;
    const int band = (j < 8) ? (15 - j) : (j - 8);
    const size_t hoff = (size_t)bh * 2048 * 64;
    const unsigned short* Qh = Q + hoff;
    const unsigned short* Kh = Kp + hoff;
    const unsigned short* Vh = Vt + hoff;      // [64][2048]
    const int q0 = band * 128;
    const int qg = q0 + w * 16 + l16;          // this lane's q column
    const int ktLast = band;

    // per-thread staging constants: 2 K-chunks + 2 V-chunks of 16B per tile
    const int pA = tid, pB = 512 + tid;
    const int rKA = pA >> 3, cKA = pA & 7;
    const int rKB = pB >> 3, cKB = pB & 7;
    const int rVA = pA >> 4, cVA = pA & 15;
    const int rVB = pB >> 4, cVB = pB & 15;
    const unsigned short* pKA = Kh + (size_t)rKA * 64 + ((cKA ^ (rKA & 7)) << 3);
    const unsigned short* pKB = Kh + (size_t)rKB * 64 + ((cKB ^ (rKB & 7)) << 3);
    const unsigned short* pVA = Vh + (size_t)rVA * 2048 + ((cVA ^ (rVA & 7)) << 3);
    const unsigned short* pVB = Vh + (size_t)rVB * 2048 + ((cVB ^ (rVB & 7)) << 3);
    const int dA = pA << 3, dB = pB << 3;      // lds offsets in shorts

    auto STAGE = [&](int buf, int k0) {
        gload_lds16(pKA + (size_t)k0 * 64, &sK[buf][dA]);
        gload_lds16(pKB + (size_t)k0 * 64, &sK[buf][dB]);
        gload_lds16(pVA + k0, &sV[buf][dA]);
        gload_lds16(pVB + k0, &sV[buf][dB]);
    };

    STAGE(0, 0);

    // Q as B-operand fragments: lane l holds Q[q=qg][d = kk*32 + lhi*8 + j]
    vbf8 qf[2];
#pragma unroll
    for (int kk = 0; kk < 2; ++kk)
        qf[kk] = *(const vbf8*)&Qh[(size_t)qg * 64 + kk * 32 + lhi * 8];

    vf4 oacc[4] = {};                 // O^T[d = dt*16+lhi*4+r][q = l16]
    float m = -1e30f, lsum = 0.f;

    for (int kt = 0; kt <= ktLast; ++kt) {
        const int cur = kt & 1;
        const int k0 = kt * 128;
        if (kt < ktLast) {
            STAGE(cur ^ 1, k0 + 128);
            asm volatile("s_waitcnt vmcnt(4)" ::: "memory");
        } else {
            asm volatile("s_waitcnt vmcnt(0)" ::: "memory");
        }
        __builtin_amdgcn_s_barrier();
        __builtin_amdgcn_sched_barrier(0);

        const unsigned short* sKc = &sK[cur][0];
        const unsigned short* sVc = &sV[cur][0];

        // S^T (log2-scaled): sc[nt] rows k = k0+nt*16+lhi*4+r, col q = l16
        vf4 sc[8] = {};
#pragma unroll
        for (int kk = 0; kk < 2; ++kk) {
#pragma unroll
            for (int nt = 0; nt < 8; ++nt) {
                int rr = nt * 16 + l16;
                vbf8 kf = *(const vbf8*)&sKc[(rr << 6) + ((((kk << 2) + lhi) ^ (rr & 7)) << 3)];
                sc[nt] = MFMA16(kf, qf[kk], sc[nt]);
            }
        }

        // causal mask on last tile only
        if (kt == ktLast) {
#pragma unroll
            for (int nt = 0; nt < 8; ++nt)
#pragma unroll
                for (int r = 0; r < 4; ++r) {
                    int kg = k0 + nt * 16 + lhi * 4 + r;
                    if (kg > qg) sc[nt][r] = -1e30f;
                }
        }

        // row max, tree-shaped; row q = qg spans lanes {l16, l16+16, l16+32, l16+48}
        float m4[8];
#pragma unroll
        for (int nt = 0; nt < 8; ++nt)
            m4[nt] = fmaxf(fmaxf(sc[nt][0], sc[nt][1]), fmaxf(sc[nt][2], sc[nt][3]));
        float pm = fmaxf(fmaxf(fmaxf(m4[0], m4[1]), fmaxf(m4[2], m4[3])),
                         fmaxf(fmaxf(m4[4], m4[5]), fmaxf(m4[6], m4[7])));
        pm = fmaxf(pm, __shfl_xor(pm, 16, 64));
        pm = fmaxf(pm, __shfl_xor(pm, 32, 64));

        // defer-max (T13): only rescale when the running max grew by > 8 (log2 units)
        if (!__all(pm - m <= 8.0f)) {
            float mn = fmaxf(m, pm);
            float alpha = exp2f(m - mn);
            lsum *= alpha;
#pragma unroll
            for (int dt = 0; dt < 4; ++dt)
#pragma unroll
                for (int r = 0; r < 4; ++r) oacc[dt][r] *= alpha;
            m = mn;
        }

        // P = exp2(S - m), tree-summed
        float rs4[8];
#pragma unroll
        for (int nt = 0; nt < 8; ++nt) {
#pragma unroll
            for (int r = 0; r < 4; ++r) sc[nt][r] = exp2f(sc[nt][r] - m);
            rs4[nt] = (sc[nt][0] + sc[nt][1]) + (sc[nt][2] + sc[nt][3]);
        }
        float rs = ((rs4[0] + rs4[1]) + (rs4[2] + rs4[3])) +
                   ((rs4[4] + rs4[5]) + (rs4[6] + rs4[7]));
        rs += __shfl_xor(rs, 16, 64);
        rs += __shfl_xor(rs, 32, 64);
        lsum += rs;

        // pack P^T to bf16 pairs with v_cvt_pk_bf16_f32
        unsigned int pk0[8], pk1[8];
#pragma unroll
        for (int nt = 0; nt < 8; ++nt) {
            pk0[nt] = cvtpk(sc[nt][0], sc[nt][1]);
            pk1[nt] = cvtpk(sc[nt][2], sc[nt][3]);
        }

        // PV: O^T += V^T * P^T. B-frag lane l needs P^T[k = kk*32 + lhi*8 + j][q=l16]:
        const int srcA = l16 + ((lhi & 1) ? 32 : 0);
        const int srcB = srcA + 16;
        const bool hiSel = (lhi >> 1) != 0;
#pragma unroll
        for (int kk = 0; kk < 4; ++kk) {
            unsigned int a0e = __shfl((int)pk0[2 * kk], srcA, 64);
            unsigned int a1e = __shfl((int)pk1[2 * kk], srcA, 64);
            unsigned int b0e = __shfl((int)pk0[2 * kk], srcB, 64);
            unsigned int b1e = __shfl((int)pk1[2 * kk], srcB, 64);
            unsigned int a0o = __shfl((int)pk0[2 * kk + 1], srcA, 64);
            unsigned int a1o = __shfl((int)pk1[2 * kk + 1], srcA, 64);
            unsigned int b0o = __shfl((int)pk0[2 * kk + 1], srcB, 64);
            unsigned int b1o = __shfl((int)pk1[2 * kk + 1], srcB, 64);
            vu4 uw;
            uw.x = hiSel ? a0o : a0e;
            uw.y = hiSel ? a1o : a1e;
            uw.z = hiSel ? b0o : b0e;
            uw.w = hiSel ? b1o : b1e;
            vbf8 pf = __builtin_bit_cast(vbf8, uw);
#pragma unroll
            for (int dt = 0; dt < 4; ++dt) {
                int rr = dt * 16 + l16;
                vbf8 vfr = *(const vbf8*)&sVc[(rr << 7) + ((((kk << 2) + lhi) ^ (rr & 7)) << 3)];
                oacc[dt] = MFMA16(vfr, pf, oacc[dt]);
            }
        }
        __builtin_amdgcn_s_barrier();      // all waves done reading buf[cur] before next stage overwrites
        __builtin_amdgcn_sched_barrier(0);
    }

    // epilogue: transpose O^T -> O via per-wave LDS strip (XOR-swizzled), coalesced bf16 store
    const float inv = 1.0f / lsum;
    unsigned short* so = &sK[0][0] + w * 1024;   // 16 q x 64 d per wave (16 KB total)
#pragma unroll
    for (int dt = 0; dt < 4; ++dt)
#pragma unroll
        for (int r = 0; r < 4; ++r)
            so[l16 * 64 + (((dt * 2 + (lhi >> 1)) ^ (l16 & 7)) << 3) + (lhi & 1) * 4 + r] =
                f2bf(oacc[dt][r] * inv);
    __syncthreads();

    const int b = bh >> 4, h = bh & 15;
    const int qr = lane >> 2;
    const int cj = lane & 3;
    vbf8 o1 = *(const vbf8*)&so[qr * 64 + (((cj * 2 + 0) ^ (qr & 7)) << 3)];
    vbf8 o2 = *(const vbf8*)&so[qr * 64 + (((cj * 2 + 1) ^ (qr & 7)) << 3)];
    const int qrow = q0 + w * 16 + qr;
    unsigned short* dst = att + ((size_t)(b * 2048 + qrow)) * 1024 + h * 64 + cj * 16;
    *(vbf8*)dst = o1;
    *(vbf8*)(dst + 8) = o2;
}

// ---------------- launcher ----------------
extern "C" void kernel_launch(void* const* d_in, const int* in_sizes, int n_in,
                              void* d_out, int out_size, void* d_ws, size_t ws_size,
                              hipStream_t stream) {
    const float* x = (const float*)d_in[0];      // [2,2048,1024]
    const float* w_qkv = (const float*)d_in[1];  // [3072,1024]
    const float* w_out = (const float*)d_in[2];  // [1024,1024]
    float* out = (float*)d_out;                  // [2,2048,1024]

    char* ws = (char*)d_ws;
    unsigned short* xb   = (unsigned short*)(ws);                        // 8 MiB
    unsigned short* wqb  = (unsigned short*)(ws + (8ull << 20));         // 6 MiB
    unsigned short* wob  = (unsigned short*)(ws + (14ull << 20));        // 2 MiB
    unsigned short* Qb   = (unsigned short*)(ws + (16ull << 20));        // 8 MiB (pre-scaled)
    unsigned short* Kb   = (unsigned short*)(ws + (24ull << 20));        // 8 MiB
    unsigned short* Vb   = (unsigned short*)(ws + (32ull << 20));        // 8 MiB (transposed)
    unsigned short* attb = (unsigned short*)(ws + (40ull << 20));        // 8 MiB

    // 1) fused conversions
    cvt_all<<<8192, 256, 0, stream>>>(x, w_qkv, w_out, xb, wqb, wob);

    // 2) QKV projection: [4096,1024] x [3072,1024]^T -> scatter to Q/K/Vt  (128x128 tiles)
    gemm_bt<1, 4><<<dim3(3072 / 128, 4096 / 128), 256, 0, stream>>>(
        xb, wqb, 4096, 3072, 1024, nullptr, Qb, Kb, Vb);

    // 3) causal attention -> attb [4096,1024] bf16
    attn_fwd4<<<16 * 32, 512, 0, stream>>>(Qb, Kb, Vb, attb);

    // 4) output projection: [4096,1024] x [1024,1024]^T -> f32 d_out  (128x64 tiles, 512 blocks)
    gemm_bt<0, 2><<<dim3(1024 / 64, 4096 / 128), 256, 0, stream>>>(
        attb, wob, 4096, 1024, 1024, out, nullptr, nullptr, nullptr);
}

// Round 12
// 105.791 us; speedup vs baseline: 1.1399x; 1.1399x over previous
//
#include <hip/hip_runtime.h>
#include <hip/hip_bf16.h>

typedef __attribute__((ext_vector_type(8))) short vbf8;   // 8 bf16 in 4 VGPRs
typedef __attribute__((ext_vector_type(4))) float vf4;    // MFMA 16x16 accumulator
typedef __attribute__((ext_vector_type(4))) unsigned int vu4;

#define MFMA16(a, b, c) __builtin_amdgcn_mfma_f32_16x16x32_bf16((a), (b), (c), 0, 0, 0)

__device__ __forceinline__ unsigned short f2bf(float f) {
    unsigned int u = __float_as_uint(f);
    u += 0x7fffu + ((u >> 16) & 1u);   // RNE
    return (unsigned short)(u >> 16);
}

// packed f32x2 -> bf16x2 (RNE), non-volatile so the scheduler can reorder
__device__ __forceinline__ unsigned int cvtpk(float a, float b) {
    unsigned int r;
    asm("v_cvt_pk_bf16_f32 %0, %1, %2" : "=v"(r) : "v"(a), "v"(b));
    return r;
}

// async global->LDS, 16B per lane. LDS dest must be linear (base + lane*16).
__device__ __forceinline__ void gload_lds16(const void* g, void* l) {
    __builtin_amdgcn_global_load_lds(
        (const __attribute__((address_space(1))) unsigned int*)(unsigned long long)g,
        (__attribute__((address_space(3))) unsigned int*)(unsigned long long)l,
        16, 0, 0);
}

// ---------------- fused f32 -> bf16 conversion (x, w_qkv, w_out in one launch) ----------------
__global__ __launch_bounds__(256) void cvt_all(
    const float* __restrict__ x, const float* __restrict__ wq, const float* __restrict__ wo,
    unsigned short* __restrict__ xb, unsigned short* __restrict__ wqb, unsigned short* __restrict__ wob)
{
    int i = blockIdx.x * 256 + threadIdx.x;   // float4 index, total 2097152
    const float* src;
    unsigned short* dst;
    int off;
    if (i < 1048576)      { src = x;  dst = xb;  off = i; }
    else if (i < 1835008) { src = wq; dst = wqb; off = i - 1048576; }
    else                  { src = wo; dst = wob; off = i - 1835008; }
    float4 v = ((const float4*)src)[off];
    ushort4 o;
    o.x = f2bf(v.x); o.y = f2bf(v.y); o.z = f2bf(v.z); o.w = f2bf(v.w);
    ((ushort4*)dst)[off] = o;
}

// ---------------- GEMM: C[M,N] = A[M,K] * Bt[N,K]^T, bf16 in, f32 acc ----------------
// BM=128, BN=NT*32 (NT=4 -> 128, NT=2 -> 64), BK=64, 4 waves (2x2).
// LDS linear, global source pre-swizzled; XCD-chunked block swizzle (T1).
// EPI=0: write f32 to Cf[M,N] (direct scalar stores — R9-proven; stores are fire-and-forget).
// EPI=1: scatter bf16 into Q (pre-scaled by 0.125*log2e) / K [bh][t][64] (direct scalar)
//        and V TRANSPOSED [bh][64][2048] (ushort4: identical segments, fewer insts).
template <int EPI, int NT>
__global__ __launch_bounds__(256) void gemm_bt(
    const unsigned short* __restrict__ A, const unsigned short* __restrict__ Bt,
    int M, int N, int K,
    float* __restrict__ Cf,
    unsigned short* __restrict__ Qo, unsigned short* __restrict__ Ko, unsigned short* __restrict__ Vo)
{
    __shared__ __align__(16) unsigned short sA[128 * 64];
    __shared__ __align__(16) unsigned short sB[NT * 32 * 64];

    const int tid = threadIdx.x;
    const int lane = tid & 63;
    const int w = tid >> 6;
    const int wr = w >> 1, wc = w & 1;
    const int l16 = lane & 15, lhi = lane >> 4;

    // XCD-aware bijective swizzle (grid size % 8 == 0 for all instantiations here)
    const int nbx = gridDim.x;
    const int lin = blockIdx.y * nbx + blockIdx.x;
    const int cpx = (nbx * gridDim.y) >> 3;
    const int swz = (lin & 7) * cpx + (lin >> 3);
    const int bm = swz / nbx, bn = swz % nbx;
    const int row0 = bm * 128, col0 = bn * (NT * 32);

    vf4 acc[4][NT] = {};

    for (int k0 = 0; k0 < K; k0 += 64) {
        // stage A: 128x64 = 1024 chunks (4/thread)
#pragma unroll
        for (int i = 0; i < 4; ++i) {
            int p = i * 256 + tid;
            int r = p >> 3, cb = p & 7;
            int cs = cb ^ (r & 7);
            gload_lds16(A + (size_t)(row0 + r) * K + k0 + (cs << 3), &sA[p << 3]);
        }
        // stage B: (NT*32)x64 chunks (NT/thread)
#pragma unroll
        for (int i = 0; i < NT; ++i) {
            int p = i * 256 + tid;
            int r = p >> 3, cb = p & 7;
            int cs = cb ^ (r & 7);
            gload_lds16(Bt + (size_t)(col0 + r) * K + k0 + (cs << 3), &sB[p << 3]);
        }
        __syncthreads();
#pragma unroll
        for (int kk = 0; kk < 2; ++kk) {
            const int cb = kk * 4 + lhi;
            vbf8 af[4], bfr[NT];
#pragma unroll
            for (int mt = 0; mt < 4; ++mt) {
                int r = wr * 64 + mt * 16 + l16;
                af[mt] = *(const vbf8*)&sA[(r << 6) + ((cb ^ (r & 7)) << 3)];
            }
#pragma unroll
            for (int nt = 0; nt < NT; ++nt) {
                int r = wc * (NT * 16) + nt * 16 + l16;
                bfr[nt] = *(const vbf8*)&sB[(r << 6) + ((cb ^ (r & 7)) << 3)];
            }
#pragma unroll
            for (int mt = 0; mt < 4; ++mt)
#pragma unroll
                for (int nt = 0; nt < NT; ++nt)
                    acc[mt][nt] = MFMA16(af[mt], bfr[nt], acc[mt][nt]);
        }
        __syncthreads();
    }

    // -------- epilogue (R9-proven direct scatter; V via ushort4) --------
    // C/D fragment layout: col = lane&15, row = (lane>>4)*4 + r
    if (EPI == 0) {
#pragma unroll
        for (int mt = 0; mt < 4; ++mt)
#pragma unroll
            for (int nt = 0; nt < NT; ++nt)
#pragma unroll
                for (int r = 0; r < 4; ++r) {
                    int row = row0 + wr * 64 + mt * 16 + lhi * 4 + r;
                    int col = col0 + wc * (NT * 16) + nt * 16 + l16;
                    Cf[(size_t)row * N + col] = acc[mt][nt][r];
                }
    } else {
        const int which = col0 >> 10;     // block-uniform (128-col tile, 1024-aligned bands)
        const int b = row0 >> 11;         // block-uniform
        if (which == 2) {
            // V transposed: 4 consecutive r = 4 consecutive t at fixed d -> ushort4
#pragma unroll
            for (int mt = 0; mt < 4; ++mt)
#pragma unroll
                for (int nt = 0; nt < NT; ++nt) {
                    int row = row0 + wr * 64 + mt * 16 + lhi * 4;
                    int col = col0 + wc * (NT * 16) + nt * 16 + l16;
                    int h = (col >> 6) & 15, d = col & 63;
                    int t = row & 2047;
                    size_t bh = (size_t)(b * 16 + h);
                    ushort4 pv;
                    pv.x = f2bf(acc[mt][nt][0]);
                    pv.y = f2bf(acc[mt][nt][1]);
                    pv.z = f2bf(acc[mt][nt][2]);
                    pv.w = f2bf(acc[mt][nt][3]);
                    *(ushort4*)&Vo[(bh * 64 + d) * 2048 + t] = pv;
                }
        } else {
            unsigned short* dstbuf = (which == 0) ? Qo : Ko;
            const float sc = (which == 0) ? 0.18033688011112042f : 1.0f;  // 0.125*log2e
#pragma unroll
            for (int mt = 0; mt < 4; ++mt)
#pragma unroll
                for (int nt = 0; nt < NT; ++nt)
#pragma unroll
                    for (int r = 0; r < 4; ++r) {
                        int row = row0 + wr * 64 + mt * 16 + lhi * 4 + r;
                        int col = col0 + wc * (NT * 16) + nt * 16 + l16;
                        int h = (col >> 6) & 15, d = col & 63;
                        int t = row & 2047;
                        size_t bh = (size_t)(b * 16 + h);
                        dstbuf[(bh * 2048 + t) * 64 + d] = f2bf(acc[mt][nt][r] * sc);
                    }
        }
    }
}

// ---------------- causal flash attention, 8 waves / 128 q rows, double-buffered KV ----------------
// (R4-proven structure: KVBLK=128, counted vmcnt, band pairing.)
// Q/K: [32 bh][2048][64] bf16 (Q pre-scaled by 0.125*log2e); Vt: [32 bh][64][2048] bf16.
// S^T = mfma(K, Q): lane owns one q column; softmax in-lane (exp2, defer-max) + 2 shfl;
// P packed via v_cvt_pk_bf16_f32, redistributed by shfl; O^T = mfma(V^T, P^T).
__global__ __launch_bounds__(512, 4) void attn_fwd4(
    const unsigned short* __restrict__ Q, const unsigned short* __restrict__ Kp,
    const unsigned short* __restrict__ Vt, unsigned short* __restrict__ att)
{
    __shared__ __align__(16) unsigned short sK[2][128 * 64];   // [t][d]
    __shared__ __align__(16) unsigned short sV[2][64 * 128];   // [d][t]

    const int tid = threadIdx.x;
    const int lane = tid & 63;
    const int w = tid >> 6;                    // 0..7
    const int l16 = lane & 15, lhi = lane >> 4;
    const int bh = blockIdx.x & 31;
    // band pairing for load balance: order 15..8 then 0..7 so the two co-resident
    // blocks per CU sum to ~15-16 tile-iterations instead of 10..24.
    const int j = blockIdx.x >> 5;
    const int band = (j < 8) ? (15 - j) : (j - 8);
    const size_t hoff = (size_t)bh * 2048 * 64;
    const unsigned short* Qh = Q + hoff;
    const unsigned short* Kh = Kp + hoff;
    const unsigned short* Vh = Vt + hoff;      // [64][2048]
    const int q0 = band * 128;
    const int qg = q0 + w * 16 + l16;          // this lane's q column
    const int ktLast = band;

    // per-thread staging constants: 2 K-chunks + 2 V-chunks of 16B per tile
    const int pA = tid, pB = 512 + tid;
    const int rKA = pA >> 3, cKA = pA & 7;
    const int rKB = pB >> 3, cKB = pB & 7;
    const int rVA = pA >> 4, cVA = pA & 15;
    const int rVB = pB >> 4, cVB = pB & 15;
    const unsigned short* pKA = Kh + (size_t)rKA * 64 + ((cKA ^ (rKA & 7)) << 3);
    const unsigned short* pKB = Kh + (size_t)rKB * 64 + ((cKB ^ (rKB & 7)) << 3);
    const unsigned short* pVA = Vh + (size_t)rVA * 2048 + ((cVA ^ (rVA & 7)) << 3);
    const unsigned short* pVB = Vh + (size_t)rVB * 2048 + ((cVB ^ (rVB & 7)) << 3);
    const int dA = pA << 3, dB = pB << 3;      // lds offsets in shorts

    auto STAGE = [&](int buf, int k0) {
        gload_lds16(pKA + (size_t)k0 * 64, &sK[buf][dA]);
        gload_lds16(pKB + (size_t)k0 * 64, &sK[buf][dB]);
        gload_lds16(pVA + k0, &sV[buf][dA]);
        gload_lds16(pVB + k0, &sV[buf][dB]);
    };

    STAGE(0, 0);

    // Q as B-operand fragments: lane l holds Q[q=qg][d = kk*32 + lhi*8 + j]
    vbf8 qf[2];
#pragma unroll
    for (int kk = 0; kk < 2; ++kk)
        qf[kk] = *(const vbf8*)&Qh[(size_t)qg * 64 + kk * 32 + lhi * 8];

    vf4 oacc[4] = {};                 // O^T[d = dt*16+lhi*4+r][q = l16]
    float m = -1e30f, lsum = 0.f;

    for (int kt = 0; kt <= ktLast; ++kt) {
        const int cur = kt & 1;
        const int k0 = kt * 128;
        if (kt < ktLast) {
            STAGE(cur ^ 1, k0 + 128);
            asm volatile("s_waitcnt vmcnt(4)" ::: "memory");
        } else {
            asm volatile("s_waitcnt vmcnt(0)" ::: "memory");
        }
        __builtin_amdgcn_s_barrier();
        __builtin_amdgcn_sched_barrier(0);

        const unsigned short* sKc = &sK[cur][0];
        const unsigned short* sVc = &sV[cur][0];

        // S^T (log2-scaled): sc[nt] rows k = k0+nt*16+lhi*4+r, col q = l16
        vf4 sc[8] = {};
#pragma unroll
        for (int kk = 0; kk < 2; ++kk) {
#pragma unroll
            for (int nt = 0; nt < 8; ++nt) {
                int rr = nt * 16 + l16;
                vbf8 kf = *(const vbf8*)&sKc[(rr << 6) + ((((kk << 2) + lhi) ^ (rr & 7)) << 3)];
                sc[nt] = MFMA16(kf, qf[kk], sc[nt]);
            }
        }

        // causal mask on last tile only
        if (kt == ktLast) {
#pragma unroll
            for (int nt = 0; nt < 8; ++nt)
#pragma unroll
                for (int r = 0; r < 4; ++r) {
                    int kg = k0 + nt * 16 + lhi * 4 + r;
                    if (kg > qg) sc[nt][r] = -1e30f;
                }
        }

        // row max, tree-shaped; row q = qg spans lanes {l16, l16+16, l16+32, l16+48}
        float m4[8];
#pragma unroll
        for (int nt = 0; nt < 8; ++nt)
            m4[nt] = fmaxf(fmaxf(sc[nt][0], sc[nt][1]), fmaxf(sc[nt][2], sc[nt][3]));
        float pm = fmaxf(fmaxf(fmaxf(m4[0], m4[1]), fmaxf(m4[2], m4[3])),
                         fmaxf(fmaxf(m4[4], m4[5]), fmaxf(m4[6], m4[7])));
        pm = fmaxf(pm, __shfl_xor(pm, 16, 64));
        pm = fmaxf(pm, __shfl_xor(pm, 32, 64));

        // defer-max (T13): only rescale when the running max grew by > 8 (log2 units)
        if (!__all(pm - m <= 8.0f)) {
            float mn = fmaxf(m, pm);
            float alpha = exp2f(m - mn);
            lsum *= alpha;
#pragma unroll
            for (int dt = 0; dt < 4; ++dt)
#pragma unroll
                for (int r = 0; r < 4; ++r) oacc[dt][r] *= alpha;
            m = mn;
        }

        // P = exp2(S - m), tree-summed
        float rs4[8];
#pragma unroll
        for (int nt = 0; nt < 8; ++nt) {
#pragma unroll
            for (int r = 0; r < 4; ++r) sc[nt][r] = exp2f(sc[nt][r] - m);
            rs4[nt] = (sc[nt][0] + sc[nt][1]) + (sc[nt][2] + sc[nt][3]);
        }
        float rs = ((rs4[0] + rs4[1]) + (rs4[2] + rs4[3])) +
                   ((rs4[4] + rs4[5]) + (rs4[6] + rs4[7]));
        rs += __shfl_xor(rs, 16, 64);
        rs += __shfl_xor(rs, 32, 64);
        lsum += rs;

        // pack P^T to bf16 pairs with v_cvt_pk_bf16_f32
        unsigned int pk0[8], pk1[8];
#pragma unroll
        for (int nt = 0; nt < 8; ++nt) {
            pk0[nt] = cvtpk(sc[nt][0], sc[nt][1]);
            pk1[nt] = cvtpk(sc[nt][2], sc[nt][3]);
        }

        // PV: O^T += V^T * P^T. B-frag lane l needs P^T[k = kk*32 + lhi*8 + j][q=l16]:
        const int srcA = l16 + ((lhi & 1) ? 32 : 0);
        const int srcB = srcA + 16;
        const bool hiSel = (lhi >> 1) != 0;
#pragma unroll
        for (int kk = 0; kk < 4; ++kk) {
            unsigned int a0e = __shfl((int)pk0[2 * kk], srcA, 64);
            unsigned int a1e = __shfl((int)pk1[2 * kk], srcA, 64);
            unsigned int b0e = __shfl((int)pk0[2 * kk], srcB, 64);
            unsigned int b1e = __shfl((int)pk1[2 * kk], srcB, 64);
            unsigned int a0o = __shfl((int)pk0[2 * kk + 1], srcA, 64);
            unsigned int a1o = __shfl((int)pk1[2 * kk + 1], srcA, 64);
            unsigned int b0o = __shfl((int)pk0[2 * kk + 1], srcB, 64);
            unsigned int b1o = __shfl((int)pk1[2 * kk + 1], srcB, 64);
            vu4 uw;
            uw.x = hiSel ? a0o : a0e;
            uw.y = hiSel ? a1o : a1e;
            uw.z = hiSel ? b0o : b0e;
            uw.w = hiSel ? b1o : b1e;
            vbf8 pf = __builtin_bit_cast(vbf8, uw);
#pragma unroll
            for (int dt = 0; dt < 4; ++dt) {
                int rr = dt * 16 + l16;
                vbf8 vfr = *(const vbf8*)&sVc[(rr << 7) + ((((kk << 2) + lhi) ^ (rr & 7)) << 3)];
                oacc[dt] = MFMA16(vfr, pf, oacc[dt]);
            }
        }
        __builtin_amdgcn_s_barrier();      // all waves done reading buf[cur] before next stage overwrites
        __builtin_amdgcn_sched_barrier(0);
    }

    // epilogue: transpose O^T -> O via per-wave LDS strip (XOR-swizzled), coalesced bf16 store
    const float inv = 1.0f / lsum;
    unsigned short* so = &sK[0][0] + w * 1024;   // 16 q x 64 d per wave (16 KB total)
#pragma unroll
    for (int dt = 0; dt < 4; ++dt)
#pragma unroll
        for (int r = 0; r < 4; ++r)
            so[l16 * 64 + (((dt * 2 + (lhi >> 1)) ^ (l16 & 7)) << 3) + (lhi & 1) * 4 + r] =
                f2bf(oacc[dt][r] * inv);
    __syncthreads();

    const int b = bh >> 4, h = bh & 15;
    const int qr = lane >> 2;
    const int cj = lane & 3;
    vbf8 o1 = *(const vbf8*)&so[qr * 64 + (((cj * 2 + 0) ^ (qr & 7)) << 3)];
    vbf8 o2 = *(const vbf8*)&so[qr * 64 + (((cj * 2 + 1) ^ (qr & 7)) << 3)];
    const int qrow = q0 + w * 16 + qr;
    unsigned short* dst = att + ((size_t)(b * 2048 + qrow)) * 1024 + h * 64 + cj * 16;
    *(vbf8*)dst = o1;
    *(vbf8*)(dst + 8) = o2;
}

// ---------------- launcher ----------------
extern "C" void kernel_launch(void* const* d_in, const int* in_sizes, int n_in,
                              void* d_out, int out_size, void* d_ws, size_t ws_size,
                              hipStream_t stream) {
    const float* x = (const float*)d_in[0];      // [2,2048,1024]
    const float* w_qkv = (const float*)d_in[1];  // [3072,1024]
    const float* w_out = (const float*)d_in[2];  // [1024,1024]
    float* out = (float*)d_out;                  // [2,2048,1024]

    char* ws = (char*)d_ws;
    unsigned short* xb   = (unsigned short*)(ws);                        // 8 MiB
    unsigned short* wqb  = (unsigned short*)(ws + (8ull << 20));         // 6 MiB
    unsigned short* wob  = (unsigned short*)(ws + (14ull << 20));        // 2 MiB
    unsigned short* Qb   = (unsigned short*)(ws + (16ull << 20));        // 8 MiB (pre-scaled)
    unsigned short* Kb   = (unsigned short*)(ws + (24ull << 20));        // 8 MiB
    unsigned short* Vb   = (unsigned short*)(ws + (32ull << 20));        // 8 MiB (transposed)
    unsigned short* attb = (unsigned short*)(ws + (40ull << 20));        // 8 MiB

    // 1) fused conversions
    cvt_all<<<8192, 256, 0, stream>>>(x, w_qkv, w_out, xb, wqb, wob);

    // 2) QKV projection: [4096,1024] x [3072,1024]^T -> scatter to Q/K/Vt  (128x128 tiles)
    gemm_bt<1, 4><<<dim3(3072 / 128, 4096 / 128), 256, 0, stream>>>(
        xb, wqb, 4096, 3072, 1024, nullptr, Qb, Kb, Vb);

    // 3) causal attention -> attb [4096,1024] bf16
    attn_fwd4<<<16 * 32, 512, 0, stream>>>(Qb, Kb, Vb, attb);

    // 4) output projection: [4096,1024] x [1024,1024]^T -> f32 d_out  (128x64 tiles, 512 blocks)
    gemm_bt<0, 2><<<dim3(1024 / 64, 4096 / 128), 256, 0, stream>>>(
        attb, wob, 4096, 1024, 1024, out, nullptr, nullptr, nullptr);
}